// Round 3
// baseline (1421.129 us; speedup 1.0000x reference)
//
#include <hip/hip_runtime.h>
#include <stdint.h>
#include <math.h>

// Problem constants: B=2, H=16, S=2048, D=64
#define BB 2
#define HH 16
#define SS 2048
#define DD 64
#define HSS ((size_t)SS * SS)            // mask per-head stride (elements)
#define QE  ((size_t)BB * HH * SS * DD)  // elements per tensor

#define WPAD 72                          // W row stride in shorts (64 + 8 pad)

typedef __attribute__((ext_vector_type(8))) short short8;   // bf16x8 MFMA frag
typedef __attribute__((ext_vector_type(4))) float float4v;  // fp32x4 accum

__device__ __forceinline__ float bflo(unsigned int u){ return __uint_as_float(u << 16); }
__device__ __forceinline__ float bfhi(unsigned int u){ return __uint_as_float(u & 0xffff0000u); }
__device__ __forceinline__ unsigned short f2bf(float f){
  unsigned int u = __float_as_uint(f);
  u += 0x7fffu + ((u >> 16) & 1u);   // RNE
  return (unsigned short)(u >> 16);
}
__device__ __forceinline__ unsigned int pk2(float lo, float hi){
  return ((unsigned int)f2bf(hi) << 16) | (unsigned int)f2bf(lo);
}

// ---------------------------------------------------------------------------
// Mask dtype detection (verified rounds 0-1).
// ---------------------------------------------------------------------------
__global__ void detect_mask_mode(const unsigned int* __restrict__ mw, int* __restrict__ mode_out){
  __shared__ int a32, af, a64;
  const int t = threadIdx.x;
  if (t == 0){ a32 = 1; af = 1; a64 = 1; }
  __syncthreads();
  int ok32 = 1, okf = 1, ok64 = 1;
  for (int idx = t; idx < 4096; idx += 256){
    const unsigned int w = mw[idx];
    if (w > 1u) ok32 = 0;
    if (w != 0u && w != 0x3F800000u) okf = 0;
    if ((idx & 1) ? (w != 0u) : (w > 1u)) ok64 = 0;
  }
  if (!ok32) atomicAnd(&a32, 0);
  if (!okf)  atomicAnd(&af, 0);
  if (!ok64) atomicAnd(&a64, 0);
  __syncthreads();
  if (t == 0){
    int mode;
    if (a64)      mode = 3;
    else if (a32) mode = 0;
    else if (af)  mode = 2;
    else          mode = 1;
    *mode_out = mode;
  }
}

// ---------------------------------------------------------------------------
// Prep: fp32 -> bf16 (scale folded for Q)
// ---------------------------------------------------------------------------
__global__ void conv_bf16_kernel(const float* __restrict__ src, unsigned short* __restrict__ dst, float scale){
  const size_t i = ((size_t)blockIdx.x * 256 + threadIdx.x) * 8;
  const float4 a = *(const float4*)(src + i);
  const float4 b = *(const float4*)(src + i + 4);
  uint4 o;
  o.x = pk2(a.x * scale, a.y * scale);
  o.y = pk2(a.z * scale, a.w * scale);
  o.z = pk2(b.x * scale, b.y * scale);
  o.w = pk2(b.z * scale, b.w * scale);
  *(uint4*)(dst + i) = o;
}

// ---------------------------------------------------------------------------
// Prep: V[b,h,k,d] fp32 -> Vt[b,h,d,k] bf16 (verified round 1)
// ---------------------------------------------------------------------------
__global__ void transp_v_kernel(const float* __restrict__ V, unsigned short* __restrict__ Vt){
  __shared__ unsigned short tile[64][66];
  const int t  = threadIdx.x;
  const int kt = blockIdx.x & 31;
  const int bh = blockIdx.x >> 5;
  {
    const int kr = t >> 2, dc = (t & 3) * 16;
    const float* src = V + ((size_t)bh * SS + (size_t)(kt * 64 + kr)) * DD + dc;
    #pragma unroll
    for (int c = 0; c < 4; ++c){
      const float4 v = *(const float4*)(src + c * 4);
      tile[kr][dc + c * 4 + 0] = f2bf(v.x);
      tile[kr][dc + c * 4 + 1] = f2bf(v.y);
      tile[kr][dc + c * 4 + 2] = f2bf(v.z);
      tile[kr][dc + c * 4 + 3] = f2bf(v.w);
    }
  }
  __syncthreads();
  {
    const int dr = t >> 2, kc = (t & 3) * 16;
    unsigned short* dst = Vt + ((size_t)bh * DD + dr) * SS + kt * 64 + kc;
    unsigned int w[8];
    #pragma unroll
    for (int p = 0; p < 8; ++p){
      w[p] = (unsigned int)tile[kc + 2*p][dr] | ((unsigned int)tile[kc + 2*p + 1][dr] << 16);
    }
    uint4 o0 = { w[0], w[1], w[2], w[3] };
    uint4 o1 = { w[4], w[5], w[6], w[7] };
    *(uint4*)(dst)     = o0;
    *(uint4*)(dst + 8) = o1;
  }
}

// ---------------------------------------------------------------------------
// Main fused kernel (retiled for occupancy).
// Block: 256 thr = 4 waves; one 16-query tile, batch b, k-chunk kc (split-k=4).
// Per k-step of 64 keys:
//  - wave w: scores for 16-key sub-tile w, ALL 16 heads (16x16x32 MFMA).
//    C-layout puts the 16 h-values of each (q,k) in one lane -> in-lane softmax.
//  - W -> LDS [h][q (x72 pad)][k] bf16, 36 KB.
//  - barrier; wave w owns heads {4w..4w+3}: O += W @ Vt via MFMA. barrier.
// Epilogue: unsafeAtomicAdd into zeroed out[b,q,h,d].
// Occupancy: 36 KB LDS + launch_bounds(256,3) -> >=3 blocks/CU (vs 1 in round 1).
// ---------------------------------------------------------------------------
__global__ __launch_bounds__(256, 3) void attn_main_kernel(
    const unsigned short* __restrict__ Qb, const unsigned short* __restrict__ Kb,
    const unsigned short* __restrict__ Vt, const void* __restrict__ mask,
    const int* __restrict__ modep, float* __restrict__ out)
{
  __shared__ unsigned short W[HH * 16 * WPAD];   // 36864 B

  const int t = threadIdx.x;
  const int wave = t >> 6, lane = t & 63, quad = lane >> 4, l16 = lane & 15;
  const int b = blockIdx.y, q0 = blockIdx.x * 16, kc = blockIdx.z;

  const int mode = *modep;
  const bool bmode = (mode == 1);
  const int msh = (mode == 3) ? 1 : 0;
  const unsigned int*  mw  = (const unsigned int*)mask;
  const unsigned char* mby = (const unsigned char*)mask;

  float4v O[4][4];   // [head-within-wave][d-tile]
  #pragma unroll
  for (int i = 0; i < 4; ++i)
    #pragma unroll
    for (int j = 0; j < 4; ++j) O[i][j] = (float4v){0.f, 0.f, 0.f, 0.f};

  const unsigned short* qbase = Qb + ((size_t)(b * HH) * SS + (size_t)(q0 + l16)) * DD + quad * 8;

  #pragma unroll 1
  for (int ks = 0; ks < 8; ++ks){
    const int k0  = (kc * 8 + ks) * 64;
    const int k0w = k0 + wave * 16;

    // ---- scores: all 16 heads for this wave's 16-key sub-tile ----
    unsigned int sp[HH][2];
    const unsigned short* kbase = Kb + ((size_t)(b * HH) * SS + (size_t)(k0w + l16)) * DD + quad * 8;
    const size_t mb0 = ((size_t)(b * HH) * SS + (size_t)(q0 + quad * 4)) * SS + (size_t)(k0w + l16);

    #pragma unroll
    for (int h = 0; h < HH; ++h){
      const unsigned short* qp = qbase + (size_t)h * (SS * DD);
      const unsigned short* kp = kbase + (size_t)h * (SS * DD);
      const short8 a0 = *(const short8*)(qp);
      const short8 a1 = *(const short8*)(qp + 32);
      const short8 b0 = *(const short8*)(kp);
      const short8 b1 = *(const short8*)(kp + 32);
      float4v c = (float4v){0.f, 0.f, 0.f, 0.f};
      c = __builtin_amdgcn_mfma_f32_16x16x32_bf16(a0, b0, c, 0, 0, 0);
      c = __builtin_amdgcn_mfma_f32_16x16x32_bf16(a1, b1, c, 0, 0, 0);

      unsigned int mv[4];
      const size_t mi = mb0 + (size_t)h * HSS;
      if (!bmode){
        #pragma unroll
        for (int r = 0; r < 4; ++r) mv[r] = mw[(mi + (size_t)r * SS) << msh];
      } else {
        #pragma unroll
        for (int r = 0; r < 4; ++r) mv[r] = (unsigned int)mby[mi + (size_t)r * SS];
      }
      #pragma unroll
      for (int r = 0; r < 4; ++r) if (mv[r]) c[r] = -INFINITY;

      sp[h][0] = pk2(c[0], c[1]);
      sp[h][1] = pk2(c[2], c[3]);
    }

    // ---- in-lane softmax over heads, write W to LDS ----
    #pragma unroll
    for (int r = 0; r < 4; ++r){
      const int row = quad * 4 + r;
      float sv[HH];
      float m = -INFINITY;
      #pragma unroll
      for (int h = 0; h < HH; ++h){
        const unsigned int u = sp[h][r >> 1];
        const float f = (r & 1) ? bfhi(u) : bflo(u);
        sv[h] = f;
        m = fmaxf(m, f);
      }
      float sum = 0.f;
      #pragma unroll
      for (int h = 0; h < HH; ++h){
        const float e = (sv[h] != -INFINITY) ? __expf(sv[h] - m) : 0.f;
        sv[h] = e;
        sum += e;
      }
      const float rinv = (sum > 0.f) ? (1.0f / sum) : 0.f;
      const int col = wave * 16 + l16;
      #pragma unroll
      for (int h = 0; h < HH; ++h){
        W[h * (16 * WPAD) + row * WPAD + col] = f2bf(sv[h] * rinv);
      }
    }
    __syncthreads();

    // ---- PV: this wave owns heads 4w..4w+3 ----
    #pragma unroll
    for (int hh = 0; hh < 4; ++hh){
      const int h = wave * 4 + hh;
      const unsigned short* vb = Vt + ((size_t)(b * HH + h) * DD + l16) * SS + k0 + quad * 8;
      #pragma unroll
      for (int kr = 0; kr < 2; ++kr){
        const short8 aw = *(const short8*)&W[h * (16 * WPAD) + l16 * WPAD + kr * 32 + quad * 8];
        #pragma unroll
        for (int dt = 0; dt < 4; ++dt){
          const short8 bv = *(const short8*)(vb + (size_t)dt * 16 * SS + kr * 32);
          O[hh][dt] = __builtin_amdgcn_mfma_f32_16x16x32_bf16(aw, bv, O[hh][dt], 0, 0, 0);
        }
      }
    }
    __syncthreads();
  }

  // ---- epilogue: atomic accumulate split-k partials ----
  #pragma unroll
  for (int hh = 0; hh < 4; ++hh){
    const int h = wave * 4 + hh;
    #pragma unroll
    for (int dt = 0; dt < 4; ++dt){
      #pragma unroll
      for (int r = 0; r < 4; ++r){
        float* op = out + (((size_t)b * SS + (size_t)(q0 + quad * 4 + r)) * HH + h) * DD + dt * 16 + l16;
        unsafeAtomicAdd(op, O[hh][dt][r]);
      }
    }
  }
}

extern "C" void kernel_launch(void* const* d_in, const int* in_sizes, int n_in,
                              void* d_out, int out_size, void* d_ws, size_t ws_size,
                              hipStream_t stream)
{
  const float* Q = (const float*)d_in[0];
  const float* K = (const float*)d_in[1];
  const float* V = (const float*)d_in[2];
  const void* mask = d_in[3];

  uintptr_t base = (uintptr_t)d_ws;
  int* mode_ptr       = (int*)base;
  unsigned short* Qb  = (unsigned short*)(base + 64);
  unsigned short* Kb  = Qb + QE;
  unsigned short* Vt  = Kb + QE;

  detect_mask_mode<<<1, 256, 0, stream>>>((const unsigned int*)mask, mode_ptr);
  conv_bf16_kernel<<<2048, 256, 0, stream>>>(Q, Qb, 0.125f);
  conv_bf16_kernel<<<2048, 256, 0, stream>>>(K, Kb, 1.0f);
  transp_v_kernel<<<BB * HH * (SS / 64), 256, 0, stream>>>(V, Vt);
  hipMemsetAsync(d_out, 0, (size_t)out_size * sizeof(float), stream);

  dim3 grid(SS / 16, BB, 4);
  attn_main_kernel<<<grid, 256, 0, stream>>>(Qb, Kb, Vt, mask, mode_ptr, (float*)d_out);
}

// Round 4
// 1168.903 us; speedup vs baseline: 1.2158x; 1.2158x over previous
//
#include <hip/hip_runtime.h>
#include <stdint.h>
#include <math.h>

// Problem constants: B=2, H=16, S=2048, D=64
#define BB 2
#define HH 16
#define SS 2048
#define DD 64
#define HSS ((size_t)SS * SS)            // mask per-head stride (elements)
#define QE  ((size_t)BB * HH * SS * DD)  // elements per tensor
#define PME ((size_t)BB * SS * SS)       // packed-mask elements (uint16)

#define WPAD 72                          // W row stride in shorts (64 + 8 pad)

typedef __attribute__((ext_vector_type(8))) short short8;   // bf16x8 MFMA frag
typedef __attribute__((ext_vector_type(4))) float float4v;  // fp32x4 accum

__device__ __forceinline__ float bflo(unsigned int u){ return __uint_as_float(u << 16); }
__device__ __forceinline__ float bfhi(unsigned int u){ return __uint_as_float(u & 0xffff0000u); }
__device__ __forceinline__ unsigned short f2bf(float f){
  unsigned int u = __float_as_uint(f);
  u += 0x7fffu + ((u >> 16) & 1u);   // RNE
  return (unsigned short)(u >> 16);
}
__device__ __forceinline__ unsigned int pk2(float lo, float hi){
  return ((unsigned int)f2bf(hi) << 16) | (unsigned int)f2bf(lo);
}

// ---------------------------------------------------------------------------
// Mask dtype detection (verified rounds 0-2).
// ---------------------------------------------------------------------------
__global__ void detect_mask_mode(const unsigned int* __restrict__ mw, int* __restrict__ mode_out){
  __shared__ int a32, af, a64;
  const int t = threadIdx.x;
  if (t == 0){ a32 = 1; af = 1; a64 = 1; }
  __syncthreads();
  int ok32 = 1, okf = 1, ok64 = 1;
  for (int idx = t; idx < 4096; idx += 256){
    const unsigned int w = mw[idx];
    if (w > 1u) ok32 = 0;
    if (w != 0u && w != 0x3F800000u) okf = 0;
    if ((idx & 1) ? (w != 0u) : (w > 1u)) ok64 = 0;
  }
  if (!ok32) atomicAnd(&a32, 0);
  if (!okf)  atomicAnd(&af, 0);
  if (!ok64) atomicAnd(&a64, 0);
  __syncthreads();
  if (t == 0){
    int mode;
    if (a64)      mode = 3;
    else if (a32) mode = 0;
    else if (af)  mode = 2;
    else          mode = 1;
    *mode_out = mode;
  }
}

// ---------------------------------------------------------------------------
// NEW: pack mask[b][h][q][k] -> pm[b][q][k] uint16 (bit h set if masked).
// Pure streaming kernel: thread owns 8 consecutive k; per h reads 32 B
// coalesced (4-byte modes) and ORs the bit. 537 MB read / 16.8 MB write.
// ---------------------------------------------------------------------------
__global__ __launch_bounds__(256) void pack_mask_kernel(
    const void* __restrict__ mask, const int* __restrict__ modep,
    unsigned short* __restrict__ pm)
{
  const int mode = *modep;
  const size_t tid  = (size_t)blockIdx.x * 256 + threadIdx.x;
  const size_t base = tid * 8;                 // flat (b,q,k), 8|SS so no q-cross
  const size_t bq   = base >> 11;              // b*SS + q
  const int    k0   = (int)(base & (SS - 1));
  const size_t b    = bq >> 11;
  const size_t q    = bq & (SS - 1);

  unsigned short outv[8] = {0,0,0,0,0,0,0,0};

  if (mode == 0 || mode == 2){                 // 4-byte elements, nonzero = masked
    const unsigned int* p = (const unsigned int*)mask;
    #pragma unroll
    for (int h = 0; h < HH; ++h){
      const size_t e = ((b * HH + h) * SS + q) * SS + k0;
      const uint4 a = *(const uint4*)(p + e);
      const uint4 c = *(const uint4*)(p + e + 4);
      const unsigned short bit = (unsigned short)(1u << h);
      if (a.x) outv[0] |= bit;  if (a.y) outv[1] |= bit;
      if (a.z) outv[2] |= bit;  if (a.w) outv[3] |= bit;
      if (c.x) outv[4] |= bit;  if (c.y) outv[5] |= bit;
      if (c.z) outv[6] |= bit;  if (c.w) outv[7] |= bit;
    }
  } else if (mode == 1){                       // 1-byte elements
    const unsigned char* p = (const unsigned char*)mask;
    #pragma unroll
    for (int h = 0; h < HH; ++h){
      const size_t e = ((b * HH + h) * SS + q) * SS + k0;
      uint2 a = *(const uint2*)(p + e);
      const unsigned short bit = (unsigned short)(1u << h);
      #pragma unroll
      for (int j = 0; j < 4; ++j){
        if ((a.x >> (8*j)) & 0xffu) outv[j]     |= bit;
        if ((a.y >> (8*j)) & 0xffu) outv[4 + j] |= bit;
      }
    }
  } else {                                     // int64: low dword decides
    const unsigned int* p = (const unsigned int*)mask;
    #pragma unroll
    for (int h = 0; h < HH; ++h){
      const size_t e = (((b * HH + h) * SS + q) * SS + k0) * 2;
      const unsigned short bit = (unsigned short)(1u << h);
      #pragma unroll
      for (int j = 0; j < 4; ++j){
        const uint4 a = *(const uint4*)(p + e + j * 4);
        if (a.x) outv[j * 2]     |= bit;
        if (a.z) outv[j * 2 + 1] |= bit;
      }
    }
  }

  uint4 w;
  w.x = (unsigned int)outv[0] | ((unsigned int)outv[1] << 16);
  w.y = (unsigned int)outv[2] | ((unsigned int)outv[3] << 16);
  w.z = (unsigned int)outv[4] | ((unsigned int)outv[5] << 16);
  w.w = (unsigned int)outv[6] | ((unsigned int)outv[7] << 16);
  *(uint4*)(pm + base) = w;
}

// ---------------------------------------------------------------------------
// Prep: fp32 -> bf16 (scale folded for Q)
// ---------------------------------------------------------------------------
__global__ void conv_bf16_kernel(const float* __restrict__ src, unsigned short* __restrict__ dst, float scale){
  const size_t i = ((size_t)blockIdx.x * 256 + threadIdx.x) * 8;
  const float4 a = *(const float4*)(src + i);
  const float4 b = *(const float4*)(src + i + 4);
  uint4 o;
  o.x = pk2(a.x * scale, a.y * scale);
  o.y = pk2(a.z * scale, a.w * scale);
  o.z = pk2(b.x * scale, b.y * scale);
  o.w = pk2(b.z * scale, b.w * scale);
  *(uint4*)(dst + i) = o;
}

// ---------------------------------------------------------------------------
// Prep: V[b,h,k,d] fp32 -> Vt[b,h,d,k] bf16 (verified round 1)
// ---------------------------------------------------------------------------
__global__ void transp_v_kernel(const float* __restrict__ V, unsigned short* __restrict__ Vt){
  __shared__ unsigned short tile[64][66];
  const int t  = threadIdx.x;
  const int kt = blockIdx.x & 31;
  const int bh = blockIdx.x >> 5;
  {
    const int kr = t >> 2, dc = (t & 3) * 16;
    const float* src = V + ((size_t)bh * SS + (size_t)(kt * 64 + kr)) * DD + dc;
    #pragma unroll
    for (int c = 0; c < 4; ++c){
      const float4 v = *(const float4*)(src + c * 4);
      tile[kr][dc + c * 4 + 0] = f2bf(v.x);
      tile[kr][dc + c * 4 + 1] = f2bf(v.y);
      tile[kr][dc + c * 4 + 2] = f2bf(v.z);
      tile[kr][dc + c * 4 + 3] = f2bf(v.w);
    }
  }
  __syncthreads();
  {
    const int dr = t >> 2, kc = (t & 3) * 16;
    unsigned short* dst = Vt + ((size_t)bh * DD + dr) * SS + kt * 64 + kc;
    unsigned int w[8];
    #pragma unroll
    for (int p = 0; p < 8; ++p){
      w[p] = (unsigned int)tile[kc + 2*p][dr] | ((unsigned int)tile[kc + 2*p + 1][dr] << 16);
    }
    uint4 o0 = { w[0], w[1], w[2], w[3] };
    uint4 o1 = { w[4], w[5], w[6], w[7] };
    *(uint4*)(dst)     = o0;
    *(uint4*)(dst + 8) = o1;
  }
}

// ---------------------------------------------------------------------------
// Main fused kernel (round-3 structure, packed mask, split-k=2).
// Block: 256 thr = 4 waves; one 16-query tile, batch b, k-chunk kc.
// Per k-step of 64 keys:
//  - wave w: scores for 16-key sub-tile w, ALL 16 heads (16x16x32 MFMA);
//    mask via ONE uint16/lane/row (bit h) from packed pm (LLC-resident).
//  - in-lane softmax over h; W -> LDS [h][q (x72 pad)][k] bf16 (36 KB).
//  - barrier; wave w owns heads {4w..4w+3}: O += W @ Vt via MFMA. barrier.
// Epilogue: unsafeAtomicAdd into zeroed out[b,q,h,d] (2 partials only).
// ---------------------------------------------------------------------------
__global__ __launch_bounds__(256, 3) void attn_main_kernel(
    const unsigned short* __restrict__ Qb, const unsigned short* __restrict__ Kb,
    const unsigned short* __restrict__ Vt, const unsigned short* __restrict__ pm,
    float* __restrict__ out)
{
  __shared__ unsigned short W[HH * 16 * WPAD];   // 36864 B

  const int t = threadIdx.x;
  const int wave = t >> 6, lane = t & 63, quad = lane >> 4, l16 = lane & 15;
  const int b = blockIdx.y, q0 = blockIdx.x * 16, kc = blockIdx.z;

  float4v O[4][4];   // [head-within-wave][d-tile]
  #pragma unroll
  for (int i = 0; i < 4; ++i)
    #pragma unroll
    for (int j = 0; j < 4; ++j) O[i][j] = (float4v){0.f, 0.f, 0.f, 0.f};

  const unsigned short* qbase = Qb + ((size_t)(b * HH) * SS + (size_t)(q0 + l16)) * DD + quad * 8;

  #pragma unroll 1
  for (int ks = 0; ks < 16; ++ks){
    const int k0  = (kc * 16 + ks) * 64;
    const int k0w = k0 + wave * 16;

    // ---- packed mask: one uint16 per (row, this-lane's k) ----
    const unsigned short* pmb = pm + ((size_t)b * SS + (size_t)(q0 + quad * 4)) * SS + (size_t)(k0w + l16);
    unsigned int m16[4];
    #pragma unroll
    for (int r = 0; r < 4; ++r) m16[r] = (unsigned int)pmb[(size_t)r * SS];

    // ---- scores: all 16 heads for this wave's 16-key sub-tile ----
    unsigned int sp[HH][2];
    const unsigned short* kbase = Kb + ((size_t)(b * HH) * SS + (size_t)(k0w + l16)) * DD + quad * 8;

    #pragma unroll
    for (int h = 0; h < HH; ++h){
      const unsigned short* qp = qbase + (size_t)h * (SS * DD);
      const unsigned short* kp = kbase + (size_t)h * (SS * DD);
      const short8 a0 = *(const short8*)(qp);
      const short8 a1 = *(const short8*)(qp + 32);
      const short8 b0 = *(const short8*)(kp);
      const short8 b1 = *(const short8*)(kp + 32);
      float4v c = (float4v){0.f, 0.f, 0.f, 0.f};
      c = __builtin_amdgcn_mfma_f32_16x16x32_bf16(a0, b0, c, 0, 0, 0);
      c = __builtin_amdgcn_mfma_f32_16x16x32_bf16(a1, b1, c, 0, 0, 0);

      #pragma unroll
      for (int r = 0; r < 4; ++r) if ((m16[r] >> h) & 1u) c[r] = -INFINITY;

      sp[h][0] = pk2(c[0], c[1]);
      sp[h][1] = pk2(c[2], c[3]);
    }

    // ---- in-lane softmax over heads, write W to LDS ----
    #pragma unroll
    for (int r = 0; r < 4; ++r){
      const int row = quad * 4 + r;
      float sv[HH];
      float m = -INFINITY;
      #pragma unroll
      for (int h = 0; h < HH; ++h){
        const unsigned int u = sp[h][r >> 1];
        const float f = (r & 1) ? bfhi(u) : bflo(u);
        sv[h] = f;
        m = fmaxf(m, f);
      }
      float sum = 0.f;
      #pragma unroll
      for (int h = 0; h < HH; ++h){
        const float e = (sv[h] != -INFINITY) ? __expf(sv[h] - m) : 0.f;
        sv[h] = e;
        sum += e;
      }
      const float rinv = (sum > 0.f) ? (1.0f / sum) : 0.f;
      const int col = wave * 16 + l16;
      #pragma unroll
      for (int h = 0; h < HH; ++h){
        W[h * (16 * WPAD) + row * WPAD + col] = f2bf(sv[h] * rinv);
      }
    }
    __syncthreads();

    // ---- PV: this wave owns heads 4w..4w+3 ----
    #pragma unroll
    for (int hh = 0; hh < 4; ++hh){
      const int h = wave * 4 + hh;
      const unsigned short* vb = Vt + ((size_t)(b * HH + h) * DD + l16) * SS + k0 + quad * 8;
      #pragma unroll
      for (int kr = 0; kr < 2; ++kr){
        const short8 aw = *(const short8*)&W[h * (16 * WPAD) + l16 * WPAD + kr * 32 + quad * 8];
        #pragma unroll
        for (int dt = 0; dt < 4; ++dt){
          const short8 bv = *(const short8*)(vb + (size_t)dt * 16 * SS + kr * 32);
          O[hh][dt] = __builtin_amdgcn_mfma_f32_16x16x32_bf16(aw, bv, O[hh][dt], 0, 0, 0);
        }
      }
    }
    __syncthreads();
  }

  // ---- epilogue: atomic accumulate split-k partials ----
  #pragma unroll
  for (int hh = 0; hh < 4; ++hh){
    const int h = wave * 4 + hh;
    #pragma unroll
    for (int dt = 0; dt < 4; ++dt){
      #pragma unroll
      for (int r = 0; r < 4; ++r){
        float* op = out + (((size_t)b * SS + (size_t)(q0 + quad * 4 + r)) * HH + h) * DD + dt * 16 + l16;
        unsafeAtomicAdd(op, O[hh][dt][r]);
      }
    }
  }
}

extern "C" void kernel_launch(void* const* d_in, const int* in_sizes, int n_in,
                              void* d_out, int out_size, void* d_ws, size_t ws_size,
                              hipStream_t stream)
{
  const float* Q = (const float*)d_in[0];
  const float* K = (const float*)d_in[1];
  const float* V = (const float*)d_in[2];
  const void* mask = d_in[3];

  uintptr_t base = (uintptr_t)d_ws;
  int* mode_ptr       = (int*)base;
  unsigned short* Qb  = (unsigned short*)(base + 64);
  unsigned short* Kb  = Qb + QE;
  unsigned short* Vt  = Kb + QE;
  unsigned short* pmp = Vt + QE;                 // 16.8 MB packed mask

  detect_mask_mode<<<1, 256, 0, stream>>>((const unsigned int*)mask, mode_ptr);
  pack_mask_kernel<<<(int)(PME / (256 * 8)), 256, 0, stream>>>(mask, mode_ptr, pmp);
  conv_bf16_kernel<<<2048, 256, 0, stream>>>(Q, Qb, 0.125f);
  conv_bf16_kernel<<<2048, 256, 0, stream>>>(K, Kb, 1.0f);
  transp_v_kernel<<<BB * HH * (SS / 64), 256, 0, stream>>>(V, Vt);
  hipMemsetAsync(d_out, 0, (size_t)out_size * sizeof(float), stream);

  dim3 grid(SS / 16, BB, 2);
  attn_main_kernel<<<grid, 256, 0, stream>>>(Qb, Kb, Vt, pmp, (float*)d_out);
}

// Round 5
// 1003.475 us; speedup vs baseline: 1.4162x; 1.1649x over previous
//
#include <hip/hip_runtime.h>
#include <stdint.h>
#include <math.h>

// Problem constants: B=2, H=16, S=2048, D=64
#define BB 2
#define HH 16
#define SS 2048
#define DD 64
#define QE  ((size_t)BB * HH * SS * DD)  // elements per tensor
#define PME ((size_t)BB * SS * SS)       // packed-mask elements (uint16)

typedef __attribute__((ext_vector_type(8))) short short8;   // bf16x8 MFMA frag
typedef __attribute__((ext_vector_type(4))) float float4v;  // fp32x4 accum

__device__ __forceinline__ float bflo(unsigned int u){ return __uint_as_float(u << 16); }
__device__ __forceinline__ float bfhi(unsigned int u){ return __uint_as_float(u & 0xffff0000u); }
__device__ __forceinline__ unsigned short f2bf(float f){
  unsigned int u = __float_as_uint(f);
  u += 0x7fffu + ((u >> 16) & 1u);   // RNE
  return (unsigned short)(u >> 16);
}
__device__ __forceinline__ unsigned int pk2(float lo, float hi){
  return ((unsigned int)f2bf(hi) << 16) | (unsigned int)f2bf(lo);
}

// ---------------------------------------------------------------------------
// Mask dtype detection (verified rounds 0-3).
// ---------------------------------------------------------------------------
__global__ void detect_mask_mode(const unsigned int* __restrict__ mw, int* __restrict__ mode_out){
  __shared__ int a32, af, a64;
  const int t = threadIdx.x;
  if (t == 0){ a32 = 1; af = 1; a64 = 1; }
  __syncthreads();
  int ok32 = 1, okf = 1, ok64 = 1;
  for (int idx = t; idx < 4096; idx += 256){
    const unsigned int w = mw[idx];
    if (w > 1u) ok32 = 0;
    if (w != 0u && w != 0x3F800000u) okf = 0;
    if ((idx & 1) ? (w != 0u) : (w > 1u)) ok64 = 0;
  }
  if (!ok32) atomicAnd(&a32, 0);
  if (!okf)  atomicAnd(&af, 0);
  if (!ok64) atomicAnd(&a64, 0);
  __syncthreads();
  if (t == 0){
    int mode;
    if (a64)      mode = 3;
    else if (a32) mode = 0;
    else if (af)  mode = 2;
    else          mode = 1;
    *mode_out = mode;
  }
}

// ---------------------------------------------------------------------------
// Pack mask[b][h][q][k] -> pm[b][q][k] uint16 (bit h set if masked).
// (verified round 3)
// ---------------------------------------------------------------------------
__global__ __launch_bounds__(256) void pack_mask_kernel(
    const void* __restrict__ mask, const int* __restrict__ modep,
    unsigned short* __restrict__ pm)
{
  const int mode = *modep;
  const size_t tid  = (size_t)blockIdx.x * 256 + threadIdx.x;
  const size_t base = tid * 8;
  const size_t bq   = base >> 11;
  const int    k0   = (int)(base & (SS - 1));
  const size_t b    = bq >> 11;
  const size_t q    = bq & (SS - 1);

  unsigned short outv[8] = {0,0,0,0,0,0,0,0};

  if (mode == 0 || mode == 2){
    const unsigned int* p = (const unsigned int*)mask;
    #pragma unroll
    for (int h = 0; h < HH; ++h){
      const size_t e = ((b * HH + h) * SS + q) * SS + k0;
      const uint4 a = *(const uint4*)(p + e);
      const uint4 c = *(const uint4*)(p + e + 4);
      const unsigned short bit = (unsigned short)(1u << h);
      if (a.x) outv[0] |= bit;  if (a.y) outv[1] |= bit;
      if (a.z) outv[2] |= bit;  if (a.w) outv[3] |= bit;
      if (c.x) outv[4] |= bit;  if (c.y) outv[5] |= bit;
      if (c.z) outv[6] |= bit;  if (c.w) outv[7] |= bit;
    }
  } else if (mode == 1){
    const unsigned char* p = (const unsigned char*)mask;
    #pragma unroll
    for (int h = 0; h < HH; ++h){
      const size_t e = ((b * HH + h) * SS + q) * SS + k0;
      uint2 a = *(const uint2*)(p + e);
      const unsigned short bit = (unsigned short)(1u << h);
      #pragma unroll
      for (int j = 0; j < 4; ++j){
        if ((a.x >> (8*j)) & 0xffu) outv[j]     |= bit;
        if ((a.y >> (8*j)) & 0xffu) outv[4 + j] |= bit;
      }
    }
  } else {
    const unsigned int* p = (const unsigned int*)mask;
    #pragma unroll
    for (int h = 0; h < HH; ++h){
      const size_t e = (((b * HH + h) * SS + q) * SS + k0) * 2;
      const unsigned short bit = (unsigned short)(1u << h);
      #pragma unroll
      for (int j = 0; j < 4; ++j){
        const uint4 a = *(const uint4*)(p + e + j * 4);
        if (a.x) outv[j * 2]     |= bit;
        if (a.z) outv[j * 2 + 1] |= bit;
      }
    }
  }

  uint4 w;
  w.x = (unsigned int)outv[0] | ((unsigned int)outv[1] << 16);
  w.y = (unsigned int)outv[2] | ((unsigned int)outv[3] << 16);
  w.z = (unsigned int)outv[4] | ((unsigned int)outv[5] << 16);
  w.w = (unsigned int)outv[6] | ((unsigned int)outv[7] << 16);
  *(uint4*)(pm + base) = w;
}

// ---------------------------------------------------------------------------
// Prep: fp32 -> bf16 (scale folded for Q)
// ---------------------------------------------------------------------------
__global__ void conv_bf16_kernel(const float* __restrict__ src, unsigned short* __restrict__ dst, float scale){
  const size_t i = ((size_t)blockIdx.x * 256 + threadIdx.x) * 8;
  const float4 a = *(const float4*)(src + i);
  const float4 b = *(const float4*)(src + i + 4);
  uint4 o;
  o.x = pk2(a.x * scale, a.y * scale);
  o.y = pk2(a.z * scale, a.w * scale);
  o.z = pk2(b.x * scale, b.y * scale);
  o.w = pk2(b.z * scale, b.w * scale);
  *(uint4*)(dst + i) = o;
}

// ---------------------------------------------------------------------------
// Prep: V[b,h,k,d] fp32 -> Vt[b,h,d,k] bf16 (verified round 1)
// ---------------------------------------------------------------------------
__global__ void transp_v_kernel(const float* __restrict__ V, unsigned short* __restrict__ Vt){
  __shared__ unsigned short tile[64][66];
  const int t  = threadIdx.x;
  const int kt = blockIdx.x & 31;
  const int bh = blockIdx.x >> 5;
  {
    const int kr = t >> 2, dc = (t & 3) * 16;
    const float* src = V + ((size_t)bh * SS + (size_t)(kt * 64 + kr)) * DD + dc;
    #pragma unroll
    for (int c = 0; c < 4; ++c){
      const float4 v = *(const float4*)(src + c * 4);
      tile[kr][dc + c * 4 + 0] = f2bf(v.x);
      tile[kr][dc + c * 4 + 1] = f2bf(v.y);
      tile[kr][dc + c * 4 + 2] = f2bf(v.z);
      tile[kr][dc + c * 4 + 3] = f2bf(v.w);
    }
  }
  __syncthreads();
  {
    const int dr = t >> 2, kc = (t & 3) * 16;
    unsigned short* dst = Vt + ((size_t)bh * DD + dr) * SS + kt * 64 + kc;
    unsigned int w[8];
    #pragma unroll
    for (int p = 0; p < 8; ++p){
      w[p] = (unsigned int)tile[kc + 2*p][dr] | ((unsigned int)tile[kc + 2*p + 1][dr] << 16);
    }
    uint4 o0 = { w[0], w[1], w[2], w[3] };
    uint4 o1 = { w[4], w[5], w[6], w[7] };
    *(uint4*)(dst)     = o0;
    *(uint4*)(dst + 8) = o1;
  }
}

// ---------------------------------------------------------------------------
// Main fused kernel — round-3 math, latency-restructured:
//  * Q A-frags staged to LDS once per block (32 KB) -> per-step Q is ds_read.
//  * Score phase: 2 chunks x 8 heads, all 16 K-frag loads issued before use
//    (2 exposed latencies per k-step instead of 16).
//  * W tile 32 KB, XOR-swizzled (round-1-verified layout, conflict-free).
//  * PV: 8 W-frags read upfront; Vt frags software-pipelined over heads.
//  * XCD-aware block swizzle: blocks sharing (b,kc) map to the same XCD so
//    the 4 MB K+Vt chunk stays in that XCD's L2.
// Grid: 512 1-D blocks (2/CU). split-k=2, atomics epilogue (verified cheap).
// ---------------------------------------------------------------------------
__global__ __launch_bounds__(256, 2) void attn_main_kernel(
    const unsigned short* __restrict__ Qb, const unsigned short* __restrict__ Kb,
    const unsigned short* __restrict__ Vt, const unsigned short* __restrict__ pm,
    float* __restrict__ out)
{
  __shared__ unsigned short Qf[HH * 2 * 512];   // 32768 B: [h][frag][lane*8]
  __shared__ unsigned short W[HH * 16 * 64];    // 32768 B: [h][row][col^swz]

  const int t = threadIdx.x;
  const int wave = t >> 6, lane = t & 63, quad = lane >> 4, l16 = lane & 15;

  // XCD swizzle: xcd = L&7 (round-robin dispatch); (b,kc) from bits 1..2 so
  // each (b,kc) owns 2 XCDs; q-tile from remaining bits.
  const int L  = blockIdx.x;
  const int b  = (L >> 1) & 1;
  const int kc = (L >> 2) & 1;
  const int q0 = (((L >> 3) << 1) | (L & 1)) * 16;

  float4v O[4][4];   // [head-within-wave][d-tile]
  #pragma unroll
  for (int i = 0; i < 4; ++i)
    #pragma unroll
    for (int j = 0; j < 4; ++j) O[i][j] = (float4v){0.f, 0.f, 0.f, 0.f};

  // ---- stage Q A-frags to LDS once (wave w stages heads 4w..4w+3) ----
  #pragma unroll
  for (int hh = 0; hh < 4; ++hh){
    const int h = wave * 4 + hh;
    const unsigned short* qp = Qb + ((size_t)(b * HH + h) * SS + (size_t)(q0 + l16)) * DD + quad * 8;
    const short8 a0 = *(const short8*)(qp);
    const short8 a1 = *(const short8*)(qp + 32);
    *(short8*)&Qf[(h * 2 + 0) * 512 + lane * 8] = a0;
    *(short8*)&Qf[(h * 2 + 1) * 512 + lane * 8] = a1;
  }
  __syncthreads();

  #pragma unroll 1
  for (int ks = 0; ks < 16; ++ks){
    const int k0  = (kc * 16 + ks) * 64;
    const int k0w = k0 + wave * 16;

    // ---- packed mask: one uint16 per (row, this lane's k) ----
    const unsigned short* pmb = pm + ((size_t)b * SS + (size_t)(q0 + quad * 4)) * SS + (size_t)(k0w + l16);
    unsigned int m16[4];
    #pragma unroll
    for (int r = 0; r < 4; ++r) m16[r] = (unsigned int)pmb[(size_t)r * SS];

    // ---- scores: all 16 heads, 2 chunks of 8 (loads batched ahead of use) ----
    unsigned int sp[HH][2];
    const unsigned short* kbase = Kb + ((size_t)(b * HH) * SS + (size_t)(k0w + l16)) * DD + quad * 8;

    #pragma unroll
    for (int ch = 0; ch < 2; ++ch){
      short8 kb0[8], kb1[8];
      #pragma unroll
      for (int j = 0; j < 8; ++j){
        const unsigned short* kp = kbase + (size_t)(ch * 8 + j) * (SS * DD);
        kb0[j] = *(const short8*)(kp);
        kb1[j] = *(const short8*)(kp + 32);
      }
      #pragma unroll
      for (int j = 0; j < 8; ++j){
        const int h = ch * 8 + j;
        const short8 a0 = *(const short8*)&Qf[(h * 2 + 0) * 512 + lane * 8];
        const short8 a1 = *(const short8*)&Qf[(h * 2 + 1) * 512 + lane * 8];
        float4v c = (float4v){0.f, 0.f, 0.f, 0.f};
        c = __builtin_amdgcn_mfma_f32_16x16x32_bf16(a0, kb0[j], c, 0, 0, 0);
        c = __builtin_amdgcn_mfma_f32_16x16x32_bf16(a1, kb1[j], c, 0, 0, 0);
        #pragma unroll
        for (int r = 0; r < 4; ++r) if ((m16[r] >> h) & 1u) c[r] = -INFINITY;
        sp[h][0] = pk2(c[0], c[1]);
        sp[h][1] = pk2(c[2], c[3]);
      }
    }

    // ---- in-lane softmax over heads, write W to LDS (XOR swizzle) ----
    #pragma unroll
    for (int r = 0; r < 4; ++r){
      const int row = quad * 4 + r;
      float sv[HH];
      float m = -INFINITY;
      #pragma unroll
      for (int h = 0; h < HH; ++h){
        const unsigned int u = sp[h][r >> 1];
        const float f = (r & 1) ? bfhi(u) : bflo(u);
        sv[h] = f;
        m = fmaxf(m, f);
      }
      float sum = 0.f;
      #pragma unroll
      for (int h = 0; h < HH; ++h){
        const float e = (sv[h] != -INFINITY) ? __expf(sv[h] - m) : 0.f;
        sv[h] = e;
        sum += e;
      }
      const float rinv = (sum > 0.f) ? (1.0f / sum) : 0.f;
      const int col = (wave * 16 + l16) ^ ((row & 7) << 3);
      #pragma unroll
      for (int h = 0; h < HH; ++h){
        W[h * 1024 + row * 64 + col] = f2bf(sv[h] * rinv);
      }
    }
    __syncthreads();

    // ---- PV: this wave owns heads 4w..4w+3; Vt loads pipelined over heads ----
    {
      short8 aw[8];
      #pragma unroll
      for (int hh = 0; hh < 4; ++hh)
        #pragma unroll
        for (int kr = 0; kr < 2; ++kr){
          const int h = wave * 4 + hh;
          aw[hh * 2 + kr] = *(const short8*)&W[h * 1024 + l16 * 64 + ((kr * 32 + quad * 8) ^ ((l16 & 7) << 3))];
        }

      short8 vb[2][8];
      {
        const unsigned short* v0 = Vt + ((size_t)(b * HH + wave * 4) * DD + l16) * SS + k0 + quad * 8;
        #pragma unroll
        for (int kr = 0; kr < 2; ++kr)
          #pragma unroll
          for (int dt = 0; dt < 4; ++dt)
            vb[0][kr * 4 + dt] = *(const short8*)(v0 + (size_t)dt * 16 * SS + kr * 32);
      }
      #pragma unroll
      for (int hh = 0; hh < 4; ++hh){
        const int cur = hh & 1;
        if (hh < 3){
          const unsigned short* v1 = Vt + ((size_t)(b * HH + wave * 4 + hh + 1) * DD + l16) * SS + k0 + quad * 8;
          #pragma unroll
          for (int kr = 0; kr < 2; ++kr)
            #pragma unroll
            for (int dt = 0; dt < 4; ++dt)
              vb[cur ^ 1][kr * 4 + dt] = *(const short8*)(v1 + (size_t)dt * 16 * SS + kr * 32);
        }
        #pragma unroll
        for (int kr = 0; kr < 2; ++kr)
          #pragma unroll
          for (int dt = 0; dt < 4; ++dt)
            O[hh][dt] = __builtin_amdgcn_mfma_f32_16x16x32_bf16(aw[hh * 2 + kr], vb[cur][kr * 4 + dt], O[hh][dt], 0, 0, 0);
      }
    }
    __syncthreads();
  }

  // ---- epilogue: atomic accumulate split-k partials ----
  #pragma unroll
  for (int hh = 0; hh < 4; ++hh){
    const int h = wave * 4 + hh;
    #pragma unroll
    for (int dt = 0; dt < 4; ++dt){
      #pragma unroll
      for (int r = 0; r < 4; ++r){
        float* op = out + (((size_t)b * SS + (size_t)(q0 + quad * 4 + r)) * HH + h) * DD + dt * 16 + l16;
        unsafeAtomicAdd(op, O[hh][dt][r]);
      }
    }
  }
}

extern "C" void kernel_launch(void* const* d_in, const int* in_sizes, int n_in,
                              void* d_out, int out_size, void* d_ws, size_t ws_size,
                              hipStream_t stream)
{
  const float* Q = (const float*)d_in[0];
  const float* K = (const float*)d_in[1];
  const float* V = (const float*)d_in[2];
  const void* mask = d_in[3];

  uintptr_t base = (uintptr_t)d_ws;
  int* mode_ptr       = (int*)base;
  unsigned short* Qb  = (unsigned short*)(base + 64);
  unsigned short* Kb  = Qb + QE;
  unsigned short* Vt  = Kb + QE;
  unsigned short* pmp = Vt + QE;                 // 16.8 MB packed mask

  detect_mask_mode<<<1, 256, 0, stream>>>((const unsigned int*)mask, mode_ptr);
  pack_mask_kernel<<<(int)(PME / (256 * 8)), 256, 0, stream>>>(mask, mode_ptr, pmp);
  conv_bf16_kernel<<<2048, 256, 0, stream>>>(Q, Qb, 0.125f);
  conv_bf16_kernel<<<2048, 256, 0, stream>>>(K, Kb, 1.0f);
  transp_v_kernel<<<BB * HH * (SS / 64), 256, 0, stream>>>(V, Vt);
  hipMemsetAsync(d_out, 0, (size_t)out_size * sizeof(float), stream);

  attn_main_kernel<<<512, 256, 0, stream>>>(Qb, Kb, Vt, pmp, (float*)d_out);
}